// Round 14
// baseline (12228.690 us; speedup 1.0000x reference)
//
#include <hip/hip_runtime.h>

#define TT 2048
#define FF 64
#define HH 256
#define ZSTR 328  // zb row stride (ushorts): 656B, bank-stride 4 -> ~2-way aliasing (free)

typedef short short8 __attribute__((ext_vector_type(8)));
typedef float f32x4 __attribute__((ext_vector_type(4)));
typedef unsigned long long u64t;
typedef unsigned u32t;

// ws layout (bytes):
//  [0)        packed bf16 weights: WhhE@0 WihE@262144 WhhD@327680 WihD@589824 WoutP@655360 (ushort idx)
//  [1343488)  hb: [2 par][8 bb][256 U][8 rp] u64 tagged h-words = 32768*8 = 262144 B
#define WS_HB_B 1343488

__device__ inline unsigned short f2b(float f) {
  unsigned int u = __builtin_bit_cast(unsigned int, f);
  u += 0x7fffu + ((u >> 16) & 1u);
  return (unsigned short)(u >> 16);
}
__device__ inline u32t pk2(float a, float b) {
  return (u32t)f2b(a) | ((u32t)f2b(b) << 16);
}

// pack fragment-linear bf16 weights into ws (unchanged)
__global__ void prep_kernel(const float* __restrict__ Wih_e, const float* __restrict__ Whh_e,
                            const float* __restrict__ Wih_d, const float* __restrict__ Whh_d,
                            const float* __restrict__ Wout, unsigned short* __restrict__ ws) {
  int idx = blockIdx.x * blockDim.x + threadIdx.x;
  if (idx >= 83968) return;
  const float* src; unsigned short* dst; int q, kdim;
  if (idx < 32768)      { q = idx;         src = Whh_e; dst = ws + 0      + q * 8; kdim = HH; }
  else if (idx < 40960) { q = idx - 32768; src = Wih_e; dst = ws + 262144 + q * 8; kdim = FF; }
  else if (idx < 73728) { q = idx - 40960; src = Whh_d; dst = ws + 327680 + q * 8; kdim = HH; }
  else if (idx < 81920) { q = idx - 73728; src = Wih_d; dst = ws + 589824 + q * 8; kdim = FF; }
  else                  { q = idx - 81920; src = Wout;  dst = ws + 655360 + q * 8; kdim = HH; }
  int ksPerTile = (kdim == HH) ? 8 : 2;
  int per = ksPerTile * 64;
  int tile = q / per, rem = q % per;
  int ks = rem / 64, l = rem % 64;
  int col = tile * 16 + (l & 15);
  int k0 = ks * 32 + (l >> 4) * 8;
#pragma unroll
  for (int e = 0; e < 8; e++) dst[e] = f2b(src[col * kdim + k0 + e]);
}

// zero tagged exchange buffer each launch
__global__ void init_hb(u64t* __restrict__ hb) {
  int i = blockIdx.x * blockDim.x + threadIdx.x;
  if (i < 32768) hb[i] = 0ull;
}

// r7-exact skeleton: 32 blocks x 256 threads (4 waves), bb = bid&7, gg = bid>>3.
// ONE mechanism changed vs r7: Whh slice staged to LDS per phase; rW hoisted to regs
// with LDS as the cheap remat backing (ds_read ~12cy vs r7's ~200cy L2 reload).
// Single zb buffer, spin -> B1 -> afr -> B2 -> MFMA -> act -> publish -> decoder.
// Exchange: tagged u64 relaxed agent atomics, fence-free, parity double-buffered (proven).
__global__ __launch_bounds__(256, 1) void lstm_kernel(
    const float* __restrict__ xg, const float* __restrict__ b_e,
    const float* __restrict__ b_d, const float* __restrict__ bout,
    const unsigned short* __restrict__ wsu, float* __restrict__ out,
    u64t* __restrict__ hb) {
  extern __shared__ unsigned short smem[];
  unsigned short* zb       = smem;         // 16*ZSTR = 5248 ushorts
  unsigned short* wout_lds = smem + 5248;  // 8 ks x 64 x 8 = 4096
  unsigned short* whh_lds  = smem + 9344;  // 16 tl x 8 ks x 64 x 8 = 65536

  const int tid = threadIdx.x;
  const int l = tid & 63, w = tid >> 6;    // 4 waves
  const int ln = l & 15, lk = l >> 4;
  const int bb = blockIdx.x & 7, gg = blockIdx.x >> 3;
  const int b0 = bb * 16;

  const int U = 64 * gg + 16 * w + ln;     // this lane's hidden unit
  const float bo_ = bout[16 * gg + ln];

  {  // stage Wout tile gg once
    const short8* WoutP = (const short8*)(wsu + 655360);
    short8* wl = (short8*)wout_lds;
    wl[tid] = WoutP[gg * 512 + tid];
    wl[tid + 256] = WoutP[gg * 512 + tid + 256];
  }

  // consumer: 6 words/thread over 192 peer units x 8 row-pairs
  int cidx[6], crow[6], cU[6];
#pragma unroll
  for (int k = 0; k < 6; k++) {
    int m = k * 256 + tid;
    int pu = m >> 3, rp = m & 7;
    int Up = pu + (pu >= 64 * gg ? 64 : 0);
    cidx[k] = (bb * 256 + Up) * 8 + rp;
    crow[k] = 2 * rp;
    cU[k] = Up;
  }
  const int p0 = (bb * 256 + U) * 8 + 2 * lk;  // producer words p0, p0+1

  float creg[4] = {0.f, 0.f, 0.f, 0.f};
  unsigned short hu[4] = {0, 0, 0, 0};         // own h (persists across phases)

  const int xrow = tid >> 4, xf = (tid & 15) * 4;
  const float* xrp = xg + (size_t)(b0 + xrow) * TT * FF + xf;
  float4 xv = *(const float4*)xrp;  // x(0)

  // prologue: zero zb h region (2048 u32)
#pragma unroll
  for (int i = 0; i < 8; i++) {
    int q = i * 256 + tid;
    *(u32t*)&zb[(q >> 7) * ZSTR + (q & 127) * 2] = 0u;
  }

  for (int ph = 0; ph < 2; ++ph) {
    const short8* WhhP = (const short8*)(wsu + (ph ? 327680 : 0));
    const short8* WihP = (const short8*)(wsu + (ph ? 589824 : 262144));
    const float* bias = ph ? b_d : b_e;

    __syncthreads();  // prior-phase LDS reads complete
    {  // stage Whh slice: 16 tiles (4 gates x 4 waves) x 8 ks x 1KB = 128KB
      short8* wl = (short8*)whh_lds;
#pragma unroll
      for (int k = 0; k < 32; k++) {
        int i = tid + 256 * k;
        int lane = i & 63, ks = (i >> 6) & 7, tl = i >> 9;
        int c = (tl >> 2) * 16 + 4 * gg + (tl & 3);
        wl[i] = WhhP[(c * 8 + ks) * 64 + lane];
      }
    }
    float bact[4];
#pragma unroll
    for (int g = 0; g < 4; g++) bact[g] = bias[g * 256 + U];
    __syncthreads();  // weights staged

    // hoisted B-fragments; LDS is the cheap remat backing if the allocator drops them
    const short8* WH = (const short8*)whh_lds;
    short8 rW[4][8];
#pragma unroll
    for (int g = 0; g < 4; g++)
#pragma unroll
      for (int ks = 0; ks < 8; ks++)
        rW[g][ks] = WH[((g * 4 + w) * 8 + ks) * 64 + l];
    short8 rX[4][2];
#pragma unroll
    for (int g = 0; g < 4; g++)
#pragma unroll
      for (int j = 0; j < 2; j++)
        rX[g][j] = WihP[((g * 16 + 4 * gg + w) * 2 + j) * 64 + l];

#pragma unroll 1
    for (int ti = 0; ti < TT; ++ti) {
      const int it = ph * TT + ti;
      const int t = ph ? (TT - 1 - ti) : ti;

      // top: stage x(t) and own h(t) into zb
      *(u32t*)&zb[xrow * ZSTR + HH + xf]     = pk2(xv.x, xv.y);
      *(u32t*)&zb[xrow * ZSTR + HH + xf + 2] = pk2(xv.z, xv.w);
      zb[(4 * lk + 0) * ZSTR + U] = hu[0];
      zb[(4 * lk + 1) * ZSTR + U] = hu[1];
      zb[(4 * lk + 2) * ZSTR + U] = hu[2];
      zb[(4 * lk + 3) * ZSTR + U] = hu[3];

      // spin on 6 peer words (tagged, relaxed agent — proven), unpack into zb
      if (it) {
        const u64t* base = hb + (size_t)(it & 1) * 16384;
        u64t v0 = 0, v1 = 0, v2 = 0, v3 = 0, v4 = 0, v5 = 0;
        bool d0 = false, d1 = false, d2 = false, d3 = false, d4 = false, d5 = false;
        do {
          if (!d0) { v0 = __hip_atomic_load(base + cidx[0], __ATOMIC_RELAXED, __HIP_MEMORY_SCOPE_AGENT);
                     d0 = ((u32t)v0 == (u32t)it); }
          if (!d1) { v1 = __hip_atomic_load(base + cidx[1], __ATOMIC_RELAXED, __HIP_MEMORY_SCOPE_AGENT);
                     d1 = ((u32t)v1 == (u32t)it); }
          if (!d2) { v2 = __hip_atomic_load(base + cidx[2], __ATOMIC_RELAXED, __HIP_MEMORY_SCOPE_AGENT);
                     d2 = ((u32t)v2 == (u32t)it); }
          if (!d3) { v3 = __hip_atomic_load(base + cidx[3], __ATOMIC_RELAXED, __HIP_MEMORY_SCOPE_AGENT);
                     d3 = ((u32t)v3 == (u32t)it); }
          if (!d4) { v4 = __hip_atomic_load(base + cidx[4], __ATOMIC_RELAXED, __HIP_MEMORY_SCOPE_AGENT);
                     d4 = ((u32t)v4 == (u32t)it); }
          if (!d5) { v5 = __hip_atomic_load(base + cidx[5], __ATOMIC_RELAXED, __HIP_MEMORY_SCOPE_AGENT);
                     d5 = ((u32t)v5 == (u32t)it); }
        } while (!(d0 && d1 && d2 && d3 && d4 && d5));
        zb[crow[0] * ZSTR + cU[0]] = (unsigned short)(v0 >> 32);
        zb[(crow[0] + 1) * ZSTR + cU[0]] = (unsigned short)(v0 >> 48);
        zb[crow[1] * ZSTR + cU[1]] = (unsigned short)(v1 >> 32);
        zb[(crow[1] + 1) * ZSTR + cU[1]] = (unsigned short)(v1 >> 48);
        zb[crow[2] * ZSTR + cU[2]] = (unsigned short)(v2 >> 32);
        zb[(crow[2] + 1) * ZSTR + cU[2]] = (unsigned short)(v2 >> 48);
        zb[crow[3] * ZSTR + cU[3]] = (unsigned short)(v3 >> 32);
        zb[(crow[3] + 1) * ZSTR + cU[3]] = (unsigned short)(v3 >> 48);
        zb[crow[4] * ZSTR + cU[4]] = (unsigned short)(v4 >> 32);
        zb[(crow[4] + 1) * ZSTR + cU[4]] = (unsigned short)(v4 >> 48);
        zb[crow[5] * ZSTR + cU[5]] = (unsigned short)(v5 >> 32);
        zb[(crow[5] + 1) * ZSTR + cU[5]] = (unsigned short)(v5 >> 48);
      }
      __syncthreads();  // B1: full z assembled

      short8 afr[10];
#pragma unroll
      for (int ks = 0; ks < 8; ks++)
        afr[ks] = *(const short8*)&zb[ln * ZSTR + ks * 32 + lk * 8];
      afr[8] = *(const short8*)&zb[ln * ZSTR + 256 + lk * 8];
      afr[9] = *(const short8*)&zb[ln * ZSTR + 288 + lk * 8];
      __syncthreads();  // B2: zb free for next-iter staging

      {  // prefetch next x
        int it2 = it + 1; if (it2 >= 2 * TT) it2 = 0;
        int t2 = (it2 < TT) ? it2 : (2 * TT - 1 - it2);
        xv = *(const float4*)(xrp + (size_t)t2 * FF);
      }

      f32x4 acc[4];
#pragma unroll
      for (int g = 0; g < 4; g++) acc[g] = f32x4{0.f, 0.f, 0.f, 0.f};
#pragma unroll
      for (int ks = 0; ks < 8; ks++)
#pragma unroll
        for (int g = 0; g < 4; g++)
          acc[g] = __builtin_amdgcn_mfma_f32_16x16x32_bf16(afr[ks], rW[g][ks], acc[g], 0, 0, 0);
#pragma unroll
      for (int j = 0; j < 2; j++)
#pragma unroll
        for (int g = 0; g < 4; g++)
          acc[g] = __builtin_amdgcn_mfma_f32_16x16x32_bf16(afr[8 + j], rX[g][j], acc[g], 0, 0, 0);

      // wave-local activation: lane holds i,f,g,o for unit U, rows 4lk+r
#pragma unroll
      for (int r = 0; r < 4; r++) {
        float gi = acc[0][r] + bact[0];
        float gf = acc[1][r] + bact[1];
        float gG = acc[2][r] + bact[2];
        float go = acc[3][r] + bact[3];
        float si = 1.f / (1.f + __expf(-gi));
        float sf = 1.f / (1.f + __expf(-gf));
        float tg = 1.f - 2.f / (__expf(2.f * gG) + 1.f);
        float so = 1.f / (1.f + __expf(-go));
        float cn = sf * creg[r] + si * tg;
        creg[r] = cn;
        float hn = so * (1.f - 2.f / (__expf(2.f * cn) + 1.f));
        hu[r] = f2b(hn);
      }

      {  // publish h(it+1) IMMEDIATELY (peers' critical path)
        u64t* bp = hb + (size_t)((it + 1) & 1) * 16384;
        const u64t tag = (u64t)(u32t)(it + 1);
        __hip_atomic_store(bp + p0,     tag | ((u64t)((u32t)hu[0] | ((u32t)hu[1] << 16)) << 32),
                           __ATOMIC_RELAXED, __HIP_MEMORY_SCOPE_AGENT);
        __hip_atomic_store(bp + p0 + 1, tag | ((u64t)((u32t)hu[2] | ((u32t)hu[3] << 16)) << 32),
                           __ATOMIC_RELAXED, __HIP_MEMORY_SCOPE_AGENT);
      }

      // decoder output (rotating wave, AFTER publish): out[:,t] = h(it) @ Wout^T + bout
      if (ph == 1 && w == (ti & 3)) {
        const short8* WO = (const short8*)wout_lds;
        f32x4 oa = {0.f, 0.f, 0.f, 0.f};
#pragma unroll
        for (int ks = 0; ks < 8; ks++)
          oa = __builtin_amdgcn_mfma_f32_16x16x32_bf16(afr[ks], WO[ks * 64 + l], oa, 0, 0, 0);
#pragma unroll
        for (int r = 0; r < 4; r++)
          out[((size_t)(b0 + 4 * lk + r) * TT + t) * FF + 16 * gg + ln] = oa[r] + bo_;
      }
    }
  }
}

extern "C" void kernel_launch(void* const* d_in, const int* in_sizes, int n_in,
                              void* d_out, int out_size, void* d_ws, size_t ws_size,
                              hipStream_t stream) {
  const float* ts    = (const float*)d_in[0];
  const float* Wih_e = (const float*)d_in[1];
  const float* Whh_e = (const float*)d_in[2];
  const float* b_e   = (const float*)d_in[3];
  const float* Wih_d = (const float*)d_in[4];
  const float* Whh_d = (const float*)d_in[5];
  const float* b_d   = (const float*)d_in[6];
  const float* Wout  = (const float*)d_in[7];
  const float* bout  = (const float*)d_in[8];
  unsigned short* ws = (unsigned short*)d_ws;
  float* out = (float*)d_out;
  u64t* hb = (u64t*)((char*)d_ws + WS_HB_B);

  const int ldsBytes = (5248 + 4096 + 65536) * 2;  // 149760 B
  (void)hipFuncSetAttribute((const void*)lstm_kernel,
                            hipFuncAttributeMaxDynamicSharedMemorySize, ldsBytes);

  prep_kernel<<<328, 256, 0, stream>>>(Wih_e, Whh_e, Wih_d, Whh_d, Wout, ws);
  init_hb<<<64, 512, 0, stream>>>(hb);
  lstm_kernel<<<32, 256, ldsBytes, stream>>>(ts, b_e, b_d, bout, ws, out, hb);
}

// Round 15
// 10681.865 us; speedup vs baseline: 1.1448x; 1.1448x over previous
//
#include <hip/hip_runtime.h>

#define TT 2048
#define FF 64
#define HH 256
#define ZSTR 328  // zb row stride (ushorts): 656B, bank-stride 4 -> ~2-way aliasing (free)

typedef short short8 __attribute__((ext_vector_type(8)));
typedef float f32x4 __attribute__((ext_vector_type(4)));
typedef unsigned long long u64t;
typedef unsigned u32t;

// ws layout (ushort units):
//  [0)       wave-contiguous weights: [ph][gg][w][f=40][lane=64][8]  (81920 chunks, 655360 ushorts)
//            f = ks*4+g (Whh, ks 0..7) then 32 + j*4+g (Wih, j 0..1); consumption order.
//  [655360)  WoutP: [4 tiles][8 ks][64][8] = 16384
//  byte 1343488: hb [2 par][8 bb][256 U][8 rp] u64 tagged h-words = 262144 B
#define WS_HB_B 1343488

__device__ inline unsigned short f2b(float f) {
  unsigned int u = __builtin_bit_cast(unsigned int, f);
  u += 0x7fffu + ((u >> 16) & 1u);
  return (unsigned short)(u >> 16);
}
__device__ inline u32t pk2(float a, float b) {
  return (u32t)f2b(a) | ((u32t)f2b(b) << 16);
}

// pack wave-contiguous fragment-linear bf16 weights into ws
__global__ void prep_kernel(const float* __restrict__ Wih_e, const float* __restrict__ Whh_e,
                            const float* __restrict__ Wih_d, const float* __restrict__ Whh_d,
                            const float* __restrict__ Wout, unsigned short* __restrict__ ws) {
  int idx = blockIdx.x * blockDim.x + threadIdx.x;
  if (idx >= 83968) return;
  unsigned short* dst = ws + idx * 8;
  if (idx < 81920) {
    int ph = idx / 40960, r = idx % 40960;
    int gg = r / 10240; r %= 10240;
    int w = r / 2560; r %= 2560;
    int f = r / 64, l = r % 64;
    const float* Whh = ph ? Whh_d : Whh_e;
    const float* Wih = ph ? Wih_d : Wih_e;
    int g = f & 3;
    int c = g * 16 + 4 * gg + w;
    int col = c * 16 + (l & 15);
    if (f < 32) {
      int ks = f >> 2;
      int k0 = ks * 32 + (l >> 4) * 8;
#pragma unroll
      for (int e = 0; e < 8; e++) dst[e] = f2b(Whh[col * HH + k0 + e]);
    } else {
      int j = (f - 32) >> 2;
      int k0 = j * 32 + (l >> 4) * 8;
#pragma unroll
      for (int e = 0; e < 8; e++) dst[e] = f2b(Wih[col * FF + k0 + e]);
    }
  } else {
    int q = idx - 81920;
    int tile = q / 512, rem = q % 512;
    int ks = rem / 64, l = rem % 64;
    int col = tile * 16 + (l & 15);
    int k0 = ks * 32 + (l >> 4) * 8;
#pragma unroll
    for (int e = 0; e < 8; e++) dst[e] = f2b(Wout[col * HH + k0 + e]);
  }
}

// zero tagged exchange buffer each launch
__global__ void init_hb(u64t* __restrict__ hb) {
  int i = blockIdx.x * blockDim.x + threadIdx.x;
  if (i < 32768) hb[i] = 0ull;
}

// r7 skeleton: 32 blocks x 256 threads (4 waves), bb = bid&7, gg = bid>>3.
// Weight stream pipelined UNDER the spin: polls issued first (retire first, in-order
// vmcnt), then 40 wave-contiguous L2 weight loads into registers; tag check waits only
// the polls; MFMA consumes weights with progressive vmcnt as they land.
// Exchange: tagged u64 relaxed agent atomics, fence-free, parity double-buffered (proven).
__global__ __launch_bounds__(256, 1) void lstm_kernel(
    const float* __restrict__ xg, const float* __restrict__ b_e,
    const float* __restrict__ b_d, const float* __restrict__ bout,
    const unsigned short* __restrict__ wsu, float* __restrict__ out,
    u64t* __restrict__ hb) {
  __shared__ unsigned short zb[16][ZSTR];
  __shared__ unsigned short wout_lds[4096];

  const int tid = threadIdx.x;
  const int l = tid & 63, w = tid >> 6;    // 4 waves
  const int ln = l & 15, lk = l >> 4;
  const int bb = blockIdx.x & 7, gg = blockIdx.x >> 3;
  const int b0 = bb * 16;

  const int U = 64 * gg + 16 * w + ln;     // this lane's hidden unit
  const float bo_ = bout[16 * gg + ln];

  {  // stage Wout tile gg once
    const short8* WoutP = (const short8*)(wsu + 655360);
    short8* wl = (short8*)wout_lds;
    wl[tid] = WoutP[gg * 512 + tid];
    wl[tid + 256] = WoutP[gg * 512 + tid + 256];
  }

  // consumer: 6 words/thread over 192 peer units x 8 row-pairs
  int cidx[6], crow[6], cU[6];
#pragma unroll
  for (int k = 0; k < 6; k++) {
    int m = k * 256 + tid;
    int pu = m >> 3, rp = m & 7;
    int Up = pu + (pu >= 64 * gg ? 64 : 0);
    cidx[k] = (bb * 256 + Up) * 8 + rp;
    crow[k] = 2 * rp;
    cU[k] = Up;
  }
  const int p0 = (bb * 256 + U) * 8 + 2 * lk;  // producer words p0, p0+1

  float creg[4] = {0.f, 0.f, 0.f, 0.f};
  unsigned short hu[4] = {0, 0, 0, 0};

  const int xrow = tid >> 4, xf = (tid & 15) * 4;
  const float* xrp = xg + (size_t)(b0 + xrow) * TT * FF + xf;
  float4 xv = *(const float4*)xrp;  // x(0)

  // prologue: zero zb h region
#pragma unroll
  for (int i = 0; i < 8; i++) {
    int q = i * 256 + tid;
    *(u32t*)&zb[q >> 7][(q & 127) * 2] = 0u;
  }

  for (int ph = 0; ph < 2; ++ph) {
    // this wave's contiguous 40KB weight region
    const short8* WB = (const short8*)(wsu + (size_t)(((ph * 4 + gg) * 4 + w)) * 20480);
    const float* bias = ph ? b_d : b_e;
    float bact[4];
#pragma unroll
    for (int g = 0; g < 4; g++) bact[g] = bias[g * 256 + U];

#pragma unroll 1
    for (int ti = 0; ti < TT; ++ti) {
      const int it = ph * TT + ti;
      const int t = ph ? (TT - 1 - ti) : ti;
      const bool need = (it != 0);

      // 1. issue round-1 polls FIRST (retire before weights; vmcnt is in-order)
      const u64t* base = hb + (size_t)(it & 1) * 16384;
      u64t v0 = 0, v1 = 0, v2 = 0, v3 = 0, v4 = 0, v5 = 0;
      if (need) {
        v0 = __hip_atomic_load(base + cidx[0], __ATOMIC_RELAXED, __HIP_MEMORY_SCOPE_AGENT);
        v1 = __hip_atomic_load(base + cidx[1], __ATOMIC_RELAXED, __HIP_MEMORY_SCOPE_AGENT);
        v2 = __hip_atomic_load(base + cidx[2], __ATOMIC_RELAXED, __HIP_MEMORY_SCOPE_AGENT);
        v3 = __hip_atomic_load(base + cidx[3], __ATOMIC_RELAXED, __HIP_MEMORY_SCOPE_AGENT);
        v4 = __hip_atomic_load(base + cidx[4], __ATOMIC_RELAXED, __HIP_MEMORY_SCOPE_AGENT);
        v5 = __hip_atomic_load(base + cidx[5], __ATOMIC_RELAXED, __HIP_MEMORY_SCOPE_AGENT);
      }
      __builtin_amdgcn_sched_barrier(0);

      // 2. issue 40 weight loads (L2-resident, wave-contiguous, consumption order)
      short8 rw[40];
#pragma unroll
      for (int f = 0; f < 40; f++) rw[f] = WB[f * 64 + l];
      __builtin_amdgcn_sched_barrier(0);

      // 3. stage x(t) and own h(t) into zb (LDS pipe, independent of vmcnt)
      *(u32t*)&zb[xrow][xf + HH]     = pk2(xv.x, xv.y);
      *(u32t*)&zb[xrow][xf + HH + 2] = pk2(xv.z, xv.w);
      zb[4 * lk + 0][U] = hu[0];
      zb[4 * lk + 1][U] = hu[1];
      zb[4 * lk + 2][U] = hu[2];
      zb[4 * lk + 3][U] = hu[3];

      // 4. tag check (waits vmcnt(40): polls only); slow path re-polls (drains weights)
      if (need) {
        bool ok = ((u32t)v0 == (u32t)it) && ((u32t)v1 == (u32t)it) &&
                  ((u32t)v2 == (u32t)it) && ((u32t)v3 == (u32t)it) &&
                  ((u32t)v4 == (u32t)it) && ((u32t)v5 == (u32t)it);
        if (!__builtin_expect(ok, 1)) {
          bool d0 = ((u32t)v0 == (u32t)it), d1 = ((u32t)v1 == (u32t)it),
               d2 = ((u32t)v2 == (u32t)it), d3 = ((u32t)v3 == (u32t)it),
               d4 = ((u32t)v4 == (u32t)it), d5 = ((u32t)v5 == (u32t)it);
          do {
            if (!d0) { v0 = __hip_atomic_load(base + cidx[0], __ATOMIC_RELAXED, __HIP_MEMORY_SCOPE_AGENT);
                       d0 = ((u32t)v0 == (u32t)it); }
            if (!d1) { v1 = __hip_atomic_load(base + cidx[1], __ATOMIC_RELAXED, __HIP_MEMORY_SCOPE_AGENT);
                       d1 = ((u32t)v1 == (u32t)it); }
            if (!d2) { v2 = __hip_atomic_load(base + cidx[2], __ATOMIC_RELAXED, __HIP_MEMORY_SCOPE_AGENT);
                       d2 = ((u32t)v2 == (u32t)it); }
            if (!d3) { v3 = __hip_atomic_load(base + cidx[3], __ATOMIC_RELAXED, __HIP_MEMORY_SCOPE_AGENT);
                       d3 = ((u32t)v3 == (u32t)it); }
            if (!d4) { v4 = __hip_atomic_load(base + cidx[4], __ATOMIC_RELAXED, __HIP_MEMORY_SCOPE_AGENT);
                       d4 = ((u32t)v4 == (u32t)it); }
            if (!d5) { v5 = __hip_atomic_load(base + cidx[5], __ATOMIC_RELAXED, __HIP_MEMORY_SCOPE_AGENT);
                       d5 = ((u32t)v5 == (u32t)it); }
          } while (!(d0 && d1 && d2 && d3 && d4 && d5));
        }
        // unpack peer h into zb
        zb[crow[0]][cU[0]] = (unsigned short)(v0 >> 32); zb[crow[0] + 1][cU[0]] = (unsigned short)(v0 >> 48);
        zb[crow[1]][cU[1]] = (unsigned short)(v1 >> 32); zb[crow[1] + 1][cU[1]] = (unsigned short)(v1 >> 48);
        zb[crow[2]][cU[2]] = (unsigned short)(v2 >> 32); zb[crow[2] + 1][cU[2]] = (unsigned short)(v2 >> 48);
        zb[crow[3]][cU[3]] = (unsigned short)(v3 >> 32); zb[crow[3] + 1][cU[3]] = (unsigned short)(v3 >> 48);
        zb[crow[4]][cU[4]] = (unsigned short)(v4 >> 32); zb[crow[4] + 1][cU[4]] = (unsigned short)(v4 >> 48);
        zb[crow[5]][cU[5]] = (unsigned short)(v5 >> 32); zb[crow[5] + 1][cU[5]] = (unsigned short)(v5 >> 48);
      }
      __syncthreads();  // B1: full z assembled

      short8 afr[10];
#pragma unroll
      for (int ks = 0; ks < 8; ks++)
        afr[ks] = *(const short8*)&zb[ln][ks * 32 + lk * 8];
      afr[8] = *(const short8*)&zb[ln][256 + lk * 8];
      afr[9] = *(const short8*)&zb[ln][288 + lk * 8];
      __syncthreads();  // B2: zb free for next-iter staging

      {  // prefetch next x
        int it2 = it + 1; if (it2 >= 2 * TT) it2 = 0;
        int t2 = (it2 < TT) ? it2 : (2 * TT - 1 - it2);
        xv = *(const float4*)(xrp + (size_t)t2 * FF);
      }

      // 5. MFMA chain: progressive vmcnt waits as rw[f] land (consumption order = issue order)
      f32x4 acc[4];
#pragma unroll
      for (int g = 0; g < 4; g++) acc[g] = f32x4{0.f, 0.f, 0.f, 0.f};
#pragma unroll
      for (int ks = 0; ks < 8; ks++)
#pragma unroll
        for (int g = 0; g < 4; g++)
          acc[g] = __builtin_amdgcn_mfma_f32_16x16x32_bf16(afr[ks], rw[ks * 4 + g], acc[g], 0, 0, 0);
#pragma unroll
      for (int j = 0; j < 2; j++)
#pragma unroll
        for (int g = 0; g < 4; g++)
          acc[g] = __builtin_amdgcn_mfma_f32_16x16x32_bf16(afr[8 + j], rw[32 + j * 4 + g], acc[g], 0, 0, 0);

      // wave-local activation: lane holds i,f,g,o for unit U, rows 4lk+r
#pragma unroll
      for (int r = 0; r < 4; r++) {
        float gi = acc[0][r] + bact[0];
        float gf = acc[1][r] + bact[1];
        float gG = acc[2][r] + bact[2];
        float go = acc[3][r] + bact[3];
        float si = 1.f / (1.f + __expf(-gi));
        float sf = 1.f / (1.f + __expf(-gf));
        float tg = 1.f - 2.f / (__expf(2.f * gG) + 1.f);
        float so = 1.f / (1.f + __expf(-go));
        float cn = sf * creg[r] + si * tg;
        creg[r] = cn;
        float hn = so * (1.f - 2.f / (__expf(2.f * cn) + 1.f));
        hu[r] = f2b(hn);
      }

      {  // publish h(it+1) IMMEDIATELY (peers' critical path)
        u64t* bp = hb + (size_t)((it + 1) & 1) * 16384;
        const u64t tag = (u64t)(u32t)(it + 1);
        __hip_atomic_store(bp + p0,     tag | ((u64t)((u32t)hu[0] | ((u32t)hu[1] << 16)) << 32),
                           __ATOMIC_RELAXED, __HIP_MEMORY_SCOPE_AGENT);
        __hip_atomic_store(bp + p0 + 1, tag | ((u64t)((u32t)hu[2] | ((u32t)hu[3] << 16)) << 32),
                           __ATOMIC_RELAXED, __HIP_MEMORY_SCOPE_AGENT);
      }

      // decoder output (rotating wave, AFTER publish): out[:,t] = h(it) @ Wout^T + bout
      if (ph == 1 && w == (ti & 3)) {
        const short8* WO = (const short8*)wout_lds;
        f32x4 oa = {0.f, 0.f, 0.f, 0.f};
#pragma unroll
        for (int ks = 0; ks < 8; ks++)
          oa = __builtin_amdgcn_mfma_f32_16x16x32_bf16(afr[ks], WO[ks * 64 + l], oa, 0, 0, 0);
#pragma unroll
        for (int r = 0; r < 4; r++)
          out[((size_t)(b0 + 4 * lk + r) * TT + t) * FF + 16 * gg + ln] = oa[r] + bo_;
      }
    }
  }
}

extern "C" void kernel_launch(void* const* d_in, const int* in_sizes, int n_in,
                              void* d_out, int out_size, void* d_ws, size_t ws_size,
                              hipStream_t stream) {
  const float* ts    = (const float*)d_in[0];
  const float* Wih_e = (const float*)d_in[1];
  const float* Whh_e = (const float*)d_in[2];
  const float* b_e   = (const float*)d_in[3];
  const float* Wih_d = (const float*)d_in[4];
  const float* Whh_d = (const float*)d_in[5];
  const float* b_d   = (const float*)d_in[6];
  const float* Wout  = (const float*)d_in[7];
  const float* bout  = (const float*)d_in[8];
  unsigned short* ws = (unsigned short*)d_ws;
  float* out = (float*)d_out;
  u64t* hb = (u64t*)((char*)d_ws + WS_HB_B);

  prep_kernel<<<328, 256, 0, stream>>>(Wih_e, Whh_e, Wih_d, Whh_d, Wout, ws);
  init_hb<<<64, 512, 0, stream>>>(hb);
  lstm_kernel<<<32, 256, 0, stream>>>(ts, b_e, b_d, bout, ws, out, hb);
}